// Round 1
// baseline (729.193 us; speedup 1.0000x reference)
//
#include <hip/hip_runtime.h>

typedef __attribute__((ext_vector_type(8))) __bf16 bf16x8;
typedef __attribute__((ext_vector_type(4))) __bf16 bf16x4;
typedef __attribute__((ext_vector_type(4))) float f32x4;

#define MFMA16(a, b, c) __builtin_amdgcn_mfma_f32_16x16x32_bf16(a, b, c, 0, 0, 0)

// Raw barrier: drains LDS ops only. __syncthreads() would force
// s_waitcnt vmcnt(0) too, stalling on fire-and-forget HBM stores and
// in-flight weight loads that nothing after the barrier reads.
#define BAR() asm volatile("s_waitcnt lgkmcnt(0)\n\ts_barrier" ::: "memory")

constexpr int HH = 224, WW = 224, CC = 256;
constexpr int HW = HH * WW;    // 50176
constexpr int SH = 3;          // shift
constexpr int NTOK = 49;       // tokens per 7x7 window

// LDS strides (bf16 elems): chosen for 16B-aligned b128 fragments + spread banks
constexpr int QS = 40;         // q/k row stride (80 B)
constexpr int VTS = 68;        // vT row stride (136 B; b64-aligned)
constexpr int PS = 72;         // P row stride (144 B)
constexpr int XSS = 264;       // xs row stride (528 B)
constexpr int SZ_QK = 2 * NTOK * QS;        // 3920  (q @0, k @1960)
// P (49*72=3528) aliases the q/k region (disjoint lifetime, barrier-separated)
constexpr int OFF_VT = SZ_QK;               // 3920
constexpr int SZ_VT = 32 * VTS;             // 2176
constexpr int XS_OFF = OFF_VT + SZ_VT;      // 6096
constexpr int SMEM_SZ = XS_OFF + NTOK * XSS;  // 19032 bf16 = 38064 B -> 4 blocks/CU

__global__ void __launch_bounds__(256) cvt_w(const float* __restrict__ w,
                                             __bf16* __restrict__ o) {
  int i = blockIdx.x * 256 + threadIdx.x;
  o[i] = (__bf16)w[i];
}

// One block = one 7x7 window. 256 threads = 4 waves cooperating on each head:
//  GEMM1: wave (wa,wb) owns mi in {2wa,2wa+1}, ni' in {3wb..3wb+2}
//  attention: wave owns output-token tile mi = wave
__global__ void __launch_bounds__(256, 4)
swin_attn(const float* __restrict__ x, const __bf16* __restrict__ wbf,
          const float* __restrict__ bias, float* __restrict__ out) {
  __shared__ __bf16 sm[SMEM_SZ];

  const int tid = threadIdx.x;
  const int lane = tid & 63;
  const int wave = tid >> 6;   // 0..3
  const int quad = lane >> 4;  // 0..3
  const int l15 = lane & 15;
  const int wa = wave >> 1, wb = wave & 1;

  // XCD swizzle: consecutive-wn windows on the same XCD's L2
  int blk = blockIdx.x;
  int win = (blk & 7) * 512 + (blk >> 3);
  int b = win >> 10;
  int hn = (win >> 5) & 31;
  int wn = win & 31;
  int r0 = hn * 7, c0 = wn * 7;

  // ---- stage rolled window: xs[tok][ch] bf16 ----
  for (int idx = tid; idx < NTOK * CC; idx += 256) {
    int c = idx / NTOK;
    int p = idx - c * NTOK;
    int pi = p / 7, pj = p - pi * 7;
    int gr = r0 + pi + SH; if (gr >= HH) gr -= HH;
    int gc = c0 + pj + SH; if (gc >= WW) gc -= WW;
    sm[XS_OFF + p * XSS + c] = (__bf16)x[((b * CC + c) * HH + gr) * WW + gc];
  }

  // per-lane output pixel (out tok = wave*16+l15), computed once per block
  int stok = wave * 16 + l15;
  bool svalid = stok < NTOK;
  int spix;
  {
    int t = svalid ? stok : 48;
    int pi = t / 7, pj = t - pi * 7;
    int gr = r0 + pi + SH; if (gr >= HH) gr -= HH;
    int gc = c0 + pj + SH; if (gc >= WW) gc -= WW;
    spix = gr * WW + gc;
  }

  __bf16* qq = sm;
  __bf16* kk = sm + NTOK * QS;
  __bf16* vT = sm + OFF_VT;
  __bf16* P = sm;                     // aliases q/k
  const float scale = 0.17677669529663687f;  // 1/sqrt(32)
  const f32x4 zero = {0.f, 0.f, 0.f, 0.f};

  for (int h = 0; h < 8; h++) {
    // (iter0: xs ready) + (prev head: all P/vT reads retired before overwrite)
    BAR();

    // ================= GEMM1: qkv tile, 2x2 wave split =================
    int oarr[3];
    float bs[3];
    f32x4 acc[2][3];
#pragma unroll
    for (int i = 0; i < 3; i++) {
      int nip = 3 * wb + i;
      int o = (nip >> 1) * 256 + h * 32 + (nip & 1) * 16 + l15;
      oarr[i] = o;
      bs[i] = bias[o];
      acc[0][i] = zero;
      acc[1][i] = zero;
    }
#pragma unroll
    for (int ks = 0; ks < 8; ks++) {
      bf16x8 bfr[3], afr[2];
#pragma unroll
      for (int i = 0; i < 3; i++)
        bfr[i] = *(const bf16x8*)(wbf + oarr[i] * 256 + ks * 32 + quad * 8);
#pragma unroll
      for (int mil = 0; mil < 2; mil++) {
        int m = (2 * wa + mil) * 16 + l15; if (m > 48) m = 48;
        afr[mil] = *(const bf16x8*)(sm + XS_OFF + m * XSS + ks * 32 + quad * 8);
      }
#pragma unroll
      for (int mil = 0; mil < 2; mil++)
#pragma unroll
        for (int i = 0; i < 3; i++)
          acc[mil][i] = MFMA16(afr[mil], bfr[i], acc[mil][i]);
    }
    // epilogue: write q/k rows (scalar b16) and vT cols (packed b64)
#pragma unroll
    for (int i = 0; i < 3; i++) {
      int nip = 3 * wb + i;
      int typ = nip >> 1;                  // 0=q 1=k 2=v
      int dl = (nip & 1) * 16 + l15;       // head-dim 0..31
#pragma unroll
      for (int mil = 0; mil < 2; mil++) {
        int mi = 2 * wa + mil;
        if (typ == 2) {
          bf16x4 pk;
#pragma unroll
          for (int r = 0; r < 4; r++) {
            int tok = mi * 16 + quad * 4 + r;
            float v = acc[mil][i][r] + bs[i];
            pk[r] = (tok < NTOK) ? (__bf16)v : (__bf16)0.f;
          }
          *(bf16x4*)(vT + dl * VTS + mi * 16 + quad * 4) = pk;
        } else {
          __bf16* tgt = typ ? kk : qq;
#pragma unroll
          for (int r = 0; r < 4; r++) {
            int tok = mi * 16 + quad * 4 + r;
            if (tok < NTOK) tgt[tok * QS + dl] = (__bf16)(acc[mil][i][r] + bs[i]);
          }
        }
      }
    }
    BAR();   // q,k,vT complete

    // ================= QK^T: wave owns row tile mi = wave =================
    int mq = wave * 16 + l15; if (mq > 48) mq = 48;
    bf16x8 aq = *(const bf16x8*)(qq + mq * QS + quad * 8);
    f32x4 sc[4];
#pragma unroll
    for (int ni = 0; ni < 4; ni++) {
      int n = ni * 16 + l15; if (n > 48) n = 48;
      bf16x8 bk = *(const bf16x8*)(kk + n * QS + quad * 8);
      sc[ni] = MFMA16(aq, bk, zero);
    }
    BAR();   // all q/k reads retired before P (alias) is written

    // ===== softmax, no max-pass (|s|<~8 -> exp safe), rows wave*16+quad*4+r =====
#pragma unroll
    for (int r = 0; r < 4; r++) {
      float e[4];
      float sum = 0.f;
#pragma unroll
      for (int ni = 0; ni < 4; ni++) {
        float s = (ni * 16 + l15 < NTOK) ? sc[ni][r] * scale : -1e30f;
        float ev = __expf(s);
        e[ni] = ev;
        sum += ev;
      }
#pragma unroll
      for (int off = 1; off < 16; off <<= 1) sum += __shfl_xor(sum, off, 64);
      float inv = 1.f / sum;
      int row = wave * 16 + quad * 4 + r;
      if (row < NTOK) {
#pragma unroll
        for (int ni = 0; ni < 4; ni++)
          P[row * PS + ni * 16 + l15] = (__bf16)(e[ni] * inv);
      }
    }
    BAR();   // P complete

    // ========== PV transposed: D^T[d][tok] = vT @ P^T, wave owns tok tile ==========
    // B-fragment of P^T == A-layout reads of P (same bytes) -> C-layout col = out tok
    f32x4 oT[2] = {zero, zero};
    int prow = wave * 16 + l15; if (prow > 48) prow = 48;
#pragma unroll
    for (int ks = 0; ks < 2; ks++) {
      bf16x8 bp = *(const bf16x8*)(P + prow * PS + ks * 32 + quad * 8);
#pragma unroll
      for (int ni2 = 0; ni2 < 2; ni2++) {
        const __bf16* vp = vT + (ni2 * 16 + l15) * VTS + ks * 32 + quad * 8;
        bf16x4 lo = *(const bf16x4*)vp;
        bf16x4 hi = *(const bf16x4*)(vp + 4);
        bf16x8 av = __builtin_shufflevector(lo, hi, 0, 1, 2, 3, 4, 5, 6, 7);
        oT[ni2] = MFMA16(av, bp, oT[ni2]);
      }
    }

    // ---- direct coalesced store from accumulators (col = token = l15) ----
    int chbase = b * CC + h * 32;
    if (svalid) {
#pragma unroll
      for (int ni2 = 0; ni2 < 2; ni2++)
#pragma unroll
        for (int r = 0; r < 4; r++) {
          int ch = chbase + ni2 * 16 + quad * 4 + r;
          out[ch * HW + spix] = oT[ni2][r];
        }
    }
  }
}

extern "C" void kernel_launch(void* const* d_in, const int* in_sizes, int n_in,
                              void* d_out, int out_size, void* d_ws, size_t ws_size,
                              hipStream_t stream) {
  const float* x = (const float*)d_in[0];
  const float* w = (const float*)d_in[1];
  const float* bs = (const float*)d_in[2];
  float* out = (float*)d_out;
  __bf16* wbf = (__bf16*)d_ws;   // 768*256*2 B scratch

  cvt_w<<<dim3(768), dim3(256), 0, stream>>>(w, wbf);
  swin_attn<<<dim3(4096), dim3(256), 0, stream>>>(x, wbf, bs, out);
}

// Round 2
// 549.219 us; speedup vs baseline: 1.3277x; 1.3277x over previous
//
#include <hip/hip_runtime.h>

typedef __attribute__((ext_vector_type(8))) __bf16 bf16x8;
typedef __attribute__((ext_vector_type(4))) __bf16 bf16x4;
typedef __attribute__((ext_vector_type(4))) float f32x4;

#define MFMA16(a, b, c) __builtin_amdgcn_mfma_f32_16x16x32_bf16(a, b, c, 0, 0, 0)

// Raw barrier: drains LDS ops only (no vmcnt(0) — stores/weight loads stay in flight)
#define BAR() asm volatile("s_waitcnt lgkmcnt(0)\n\ts_barrier" ::: "memory")

constexpr int HH = 224, WW = 224, CC = 256;
constexpr int HW = HH * WW;    // 50176
constexpr int SH = 3;          // shift
constexpr int NTOK = 49;       // tokens per 7x7 window

// LDS strides (bf16 elems): chosen for 16B-aligned b128 fragments + spread banks
constexpr int QS = 40;         // q/k row stride (80 B)
constexpr int VTS = 68;        // vT row stride (136 B; b64-aligned)
constexpr int PS = 72;         // P row stride (144 B)
constexpr int XSS = 264;       // xs row stride (528 B)
constexpr int SZ_QK = 2 * NTOK * QS;        // 3920  (q @0, k @1960)
// P (49*72=3528) aliases the q/k region (disjoint lifetime, barrier-separated)
constexpr int OFF_VT = SZ_QK;               // 3920
constexpr int SZ_VT = 32 * VTS;             // 2176
constexpr int XS_OFF = OFF_VT + SZ_VT;      // 6096
constexpr int SMEM_SZ = XS_OFF + NTOK * XSS;  // 19032 bf16 = 38064 B -> 4 blocks/CU

// Re-layout weights into per-wave fragment order so GEMM1's B-loads are
// lane-contiguous (1KB/instr, 16 lines) instead of 512B-strided 64-line gathers.
// wfrag[g=h*6+nip][ks][quad][l15][e]  (4096 elems per g)
__global__ void __launch_bounds__(256) cvt_w(const float* __restrict__ w,
                                             __bf16* __restrict__ o) {
  int i = blockIdx.x * 256 + threadIdx.x;   // 768*256 = 196608 = 768x256
  int e = i & 7;
  int l15 = (i >> 3) & 15;
  int quad = (i >> 7) & 3;
  int ks = (i >> 9) & 7;
  int g = i >> 12;                 // 0..47 = h*6 + nip
  int h = g / 6, nip = g - h * 6;
  int row = (nip >> 1) * 256 + h * 32 + (nip & 1) * 16 + l15;
  int col = ks * 32 + quad * 8 + e;
  o[i] = (__bf16)w[row * 256 + col];
}

// One block = one 7x7 window. 256 threads = 4 waves cooperating on each head:
//  GEMM1: wave (wa,wb) owns mi in {2wa,2wa+1}, ni' in {3wb..3wb+2}
//  attention: wave owns output-token tile mi = wave
__global__ void __launch_bounds__(256, 4)
swin_attn(const float* __restrict__ x, const __bf16* __restrict__ wbf,
          const float* __restrict__ bias, float* __restrict__ out) {
  __shared__ __bf16 sm[SMEM_SZ];

  const int tid = threadIdx.x;
  const int lane = tid & 63;
  const int wave = tid >> 6;   // 0..3
  const int quad = lane >> 4;  // 0..3
  const int l15 = lane & 15;
  const int wa = wave >> 1, wb = wave & 1;

  // XCD swizzle: consecutive-wn windows on the same XCD's L2
  int blk = blockIdx.x;
  int win = (blk & 7) * 512 + (blk >> 3);
  int b = win >> 10;
  int hn = (win >> 5) & 31;
  int wn = win & 31;
  int r0 = hn * 7, c0 = wn * 7;

  // ---- stage rolled window: xs[tok][ch] bf16 ----
  for (int idx = tid; idx < NTOK * CC; idx += 256) {
    int c = idx / NTOK;
    int p = idx - c * NTOK;
    int pi = p / 7, pj = p - pi * 7;
    int gr = r0 + pi + SH; if (gr >= HH) gr -= HH;
    int gc = c0 + pj + SH; if (gc >= WW) gc -= WW;
    sm[XS_OFF + p * XSS + c] = (__bf16)x[((b * CC + c) * HH + gr) * WW + gc];
  }

  // per-lane output pixel (out tok = wave*16+l15), computed once per block
  int stok = wave * 16 + l15;
  bool svalid = stok < NTOK;
  int spix;
  {
    int t = svalid ? stok : 48;
    int pi = t / 7, pj = t - pi * 7;
    int gr = r0 + pi + SH; if (gr >= HH) gr -= HH;
    int gc = c0 + pj + SH; if (gc >= WW) gc -= WW;
    spix = gr * WW + gc;
  }

  __bf16* qq = sm;
  __bf16* kk = sm + NTOK * QS;
  __bf16* vT = sm + OFF_VT;
  __bf16* P = sm;                     // aliases q/k
  const float scale = 0.17677669529663687f;  // 1/sqrt(32)
  const f32x4 zero = {0.f, 0.f, 0.f, 0.f};

  // head-invariant per-lane offset into the fragment-ordered weight array
  const __bf16* wlane = wbf + quad * 128 + l15 * 8;

  for (int h = 0; h < 8; h++) {
    // (iter0: xs ready) + (prev head: all P/vT reads retired before overwrite)
    BAR();

    // ================= GEMM1: qkv tile, 2x2 wave split =================
    float bs[3];
    f32x4 acc[2][3];
#pragma unroll
    for (int i = 0; i < 3; i++) {
      int nip = 3 * wb + i;
      int o = (nip >> 1) * 256 + h * 32 + (nip & 1) * 16 + l15;
      bs[i] = bias[o];
      acc[0][i] = zero;
      acc[1][i] = zero;
    }
    // fragment base for this head / wave-half: g = h*6 + 3*wb + i
    const __bf16* wp = wlane + (h * 6 + 3 * wb) * 4096;

    // depth-4 prefetch ring: 12 coalesced 1KB loads in flight
    bf16x8 wfr[4][3];
#pragma unroll
    for (int pk = 0; pk < 4; pk++)
#pragma unroll
      for (int i = 0; i < 3; i++)
        wfr[pk][i] = *(const bf16x8*)(wp + i * 4096 + pk * 512);

#pragma unroll
    for (int ks = 0; ks < 8; ks++) {
      bf16x8 bfr[3], afr[2];
#pragma unroll
      for (int i = 0; i < 3; i++) bfr[i] = wfr[ks & 3][i];
      if (ks < 4) {
#pragma unroll
        for (int i = 0; i < 3; i++)
          wfr[ks & 3][i] = *(const bf16x8*)(wp + i * 4096 + (ks + 4) * 512);
      }
#pragma unroll
      for (int mil = 0; mil < 2; mil++) {
        int m = (2 * wa + mil) * 16 + l15; if (m > 48) m = 48;
        afr[mil] = *(const bf16x8*)(sm + XS_OFF + m * XSS + ks * 32 + quad * 8);
      }
#pragma unroll
      for (int mil = 0; mil < 2; mil++)
#pragma unroll
        for (int i = 0; i < 3; i++)
          acc[mil][i] = MFMA16(afr[mil], bfr[i], acc[mil][i]);
    }
    // epilogue: write q/k rows (scalar b16) and vT cols (packed b64)
#pragma unroll
    for (int i = 0; i < 3; i++) {
      int nip = 3 * wb + i;
      int typ = nip >> 1;                  // 0=q 1=k 2=v
      int dl = (nip & 1) * 16 + l15;       // head-dim 0..31
#pragma unroll
      for (int mil = 0; mil < 2; mil++) {
        int mi = 2 * wa + mil;
        if (typ == 2) {
          bf16x4 pk;
#pragma unroll
          for (int r = 0; r < 4; r++) {
            int tok = mi * 16 + quad * 4 + r;
            float v = acc[mil][i][r] + bs[i];
            pk[r] = (tok < NTOK) ? (__bf16)v : (__bf16)0.f;
          }
          *(bf16x4*)(vT + dl * VTS + mi * 16 + quad * 4) = pk;
        } else {
          __bf16* tgt = typ ? kk : qq;
#pragma unroll
          for (int r = 0; r < 4; r++) {
            int tok = mi * 16 + quad * 4 + r;
            if (tok < NTOK) tgt[tok * QS + dl] = (__bf16)(acc[mil][i][r] + bs[i]);
          }
        }
      }
    }
    BAR();   // q,k,vT complete

    // ================= QK^T: wave owns row tile mi = wave =================
    int mq = wave * 16 + l15; if (mq > 48) mq = 48;
    bf16x8 aq = *(const bf16x8*)(qq + mq * QS + quad * 8);
    f32x4 sc[4];
#pragma unroll
    for (int ni = 0; ni < 4; ni++) {
      int n = ni * 16 + l15; if (n > 48) n = 48;
      bf16x8 bk = *(const bf16x8*)(kk + n * QS + quad * 8);
      sc[ni] = MFMA16(aq, bk, zero);
    }
    BAR();   // all q/k reads retired before P (alias) is written

    // ===== softmax, no max-pass (|s|<~8 -> exp safe), rows wave*16+quad*4+r =====
#pragma unroll
    for (int r = 0; r < 4; r++) {
      float e[4];
      float sum = 0.f;
#pragma unroll
      for (int ni = 0; ni < 4; ni++) {
        float s = (ni * 16 + l15 < NTOK) ? sc[ni][r] * scale : -1e30f;
        float ev = __expf(s);
        e[ni] = ev;
        sum += ev;
      }
#pragma unroll
      for (int off = 1; off < 16; off <<= 1) sum += __shfl_xor(sum, off, 64);
      float inv = 1.f / sum;
      int row = wave * 16 + quad * 4 + r;
      if (row < NTOK) {
#pragma unroll
        for (int ni = 0; ni < 4; ni++)
          P[row * PS + ni * 16 + l15] = (__bf16)(e[ni] * inv);
      }
    }
    BAR();   // P complete

    // ========== PV transposed: D^T[d][tok] = vT @ P^T, wave owns tok tile ==========
    // B-fragment of P^T == A-layout reads of P (same bytes) -> C-layout col = out tok
    f32x4 oT[2] = {zero, zero};
    int prow = wave * 16 + l15; if (prow > 48) prow = 48;
#pragma unroll
    for (int ks = 0; ks < 2; ks++) {
      bf16x8 bp = *(const bf16x8*)(P + prow * PS + ks * 32 + quad * 8);
#pragma unroll
      for (int ni2 = 0; ni2 < 2; ni2++) {
        const __bf16* vp = vT + (ni2 * 16 + l15) * VTS + ks * 32 + quad * 8;
        bf16x4 lo = *(const bf16x4*)vp;
        bf16x4 hi = *(const bf16x4*)(vp + 4);
        bf16x8 av = __builtin_shufflevector(lo, hi, 0, 1, 2, 3, 4, 5, 6, 7);
        oT[ni2] = MFMA16(av, bp, oT[ni2]);
      }
    }

    // ---- direct coalesced store from accumulators (col = token = l15) ----
    int chbase = b * CC + h * 32;
    if (svalid) {
#pragma unroll
      for (int ni2 = 0; ni2 < 2; ni2++)
#pragma unroll
        for (int r = 0; r < 4; r++) {
          int ch = chbase + ni2 * 16 + quad * 4 + r;
          out[ch * HW + spix] = oT[ni2][r];
        }
    }
  }
}

extern "C" void kernel_launch(void* const* d_in, const int* in_sizes, int n_in,
                              void* d_out, int out_size, void* d_ws, size_t ws_size,
                              hipStream_t stream) {
  const float* x = (const float*)d_in[0];
  const float* w = (const float*)d_in[1];
  const float* bs = (const float*)d_in[2];
  float* out = (float*)d_out;
  __bf16* wbf = (__bf16*)d_ws;   // 768*256*2 B scratch

  cvt_w<<<dim3(768), dim3(256), 0, stream>>>(w, wbf);
  swin_attn<<<dim3(4096), dim3(256), 0, stream>>>(x, wbf, bs, out);
}